// Round 13
// baseline (264.499 us; speedup 1.0000x reference)
//
#include <hip/hip_runtime.h>
#include <math.h>

#define DI __device__ __forceinline__

namespace {

constexpr int PB = 32768;   // batch

typedef _Float16 half_t;
typedef float f32x4 __attribute__((ext_vector_type(4)));
typedef _Float16 f16x8 __attribute__((ext_vector_type(8)));

#define MFMA16 __builtin_amdgcn_mfma_f32_16x16x32_f16

DI void gl16(const void* g, void* l) {
  __builtin_amdgcn_global_load_lds((const __attribute__((address_space(1))) void*)g,
                                   (__attribute__((address_space(3))) void*)l, 16, 0, 0);
}
DI f16x8 asH(f32x4 v) { return __builtin_bit_cast(f16x8, v); }

// single-plane fragment-major index:
// chunk = (k>>5)*(P/16) + (c>>4); within chunk: ((k>>3)&3)*128 + (c&15)*8 + (k&7)
DI size_t fragIdx1(int c, int k, int P) {
  return (size_t)((k >> 5)*(P >> 4) + (c >> 4))*512
       + ((k >> 3) & 3)*128 + (c & 15)*8 + (k & 7);
}

// ---------------- precompute kernels (all tiny) ----------------

__global__ void k_weff(const float* __restrict__ Wqkv, const float* __restrict__ bqkv,
                       const float* __restrict__ Wo, const float* __restrict__ bo,
                       float* __restrict__ M, float* __restrict__ beff)
{
  const int i = blockIdx.x >> 7;
  const int c = blockIdx.x & 127;
  const int k = threadIdx.x;
  const float* wo_row = Wo + (size_t)(i*128 + c)*128;
  const float* wv = Wqkv + (size_t)(i*384 + 256)*128;
  float acc = 0.f;
#pragma unroll 4
  for (int j = 0; j < 128; ++j)
    acc = fmaf(wo_row[j], wv[j*128 + k], acc);
  M[(size_t)(i*128 + c)*128 + k] = acc;

  __shared__ float red[128];
  const float* bv = bqkv + i*384 + 256;
  red[k] = wo_row[k] * bv[k];
  __syncthreads();
  for (int s = 64; s > 0; s >>= 1) {
    if (k < s) red[k] += red[k + s];
    __syncthreads();
  }
  if (k == 0) beff[i*128 + c] = red[0] + bo[i*128 + c];
}

// N fragments (P=256, K chunks 0..24): 4096*(Wf1·M); k=768+i col = 4096*cvec_i; pad zero
__global__ void k_nbig2(const float* __restrict__ Wf1, const float* __restrict__ M,
                        const float* __restrict__ beff, half_t* __restrict__ Nf)
{
  const int i = blockIdx.x >> 8;
  const int c = blockIdx.x & 255;
  const int k = threadIdx.x;
  const float* w_row = Wf1 + (size_t)c*768 + i*128;
  const float* Mi = M + (size_t)i*128*128;
  float acc = 0.f;
#pragma unroll 4
  for (int j = 0; j < 128; ++j)
    acc = fmaf(w_row[j], Mi[j*128 + k], acc);
  Nf[fragIdx1(c, i*128 + k, 256)] = (half_t)(acc * 4096.f);

  __shared__ float red[128];
  red[k] = w_row[k] * beff[i*128 + k];
  __syncthreads();
  for (int s = 64; s > 0; s >>= 1) {
    if (k < s) red[k] += red[k + s];
    __syncthreads();
  }
  if (k == 0)
    Nf[fragIdx1(c, 768 + i, 256)] = (half_t)(red[0] * 4096.f);
  if (i == 0 && k < 26)
    Nf[fragIdx1(c, 774 + k, 256)] = (half_t)0.f;
}

// merged ghat (blocks 0..17) + svec (blocks 18..23)
__global__ void k_gsv(const float* __restrict__ M, const float* __restrict__ Wg,
                      const float* __restrict__ beff, const float* __restrict__ bg,
                      float* __restrict__ Ghat, float* __restrict__ svec)
{
  const int bid = blockIdx.x;
  const int k = threadIdx.x;
  if (bid < 18) {
    const int j = bid / 3;
    const int src = bid % 3;
    int i0, i1;
    if (src == 0)      { i0 = 2; i1 = 4; }
    else if (src == 1) { i0 = 0; i1 = 5; }
    else               { i0 = 1; i1 = 3; }
    float acc = 0.f;
    for (int t = 0; t < 2; ++t) {
      const int i = t ? i1 : i0;
      const float* Mi = M + (size_t)i*128*128;
      const float* wg = Wg + j*768 + i*128;
#pragma unroll 4
      for (int c = 0; c < 128; ++c)
        acc = fmaf(Mi[c*128 + k], wg[c], acc);
    }
    Ghat[j*384 + src*128 + k] = acc;
  } else {
    const int j = bid - 18;
    float p = 0.f;
#pragma unroll
    for (int i = 0; i < 6; ++i)
      p = fmaf(beff[i*128 + k], Wg[j*768 + i*128 + k], p);
    __shared__ float red[128];
    red[k] = p;
    __syncthreads();
    for (int s = 64; s > 0; s >>= 1) {
      if (k < s) red[k] += red[k + s];
      __syncthreads();
    }
    if (k == 0) svec[j] = red[0] + bg[j];
  }
}

// merged fp32->f16 fragment-major split for all four weight tensors
__global__ void k_splitall(const float* __restrict__ Wt, const float* __restrict__ Wv,
                           const float* __restrict__ Wa, const float* __restrict__ Wf2,
                           half_t* __restrict__ Wft, half_t* __restrict__ Wfv,
                           half_t* __restrict__ Wfa, half_t* __restrict__ WF2)
{
  const int idx = blockIdx.x*256 + threadIdx.x;
  const float* in; half_t* outb; int local, P, KD;
  if (idx < 98304)        { in = Wt;  outb = Wft; local = idx;          P = 128; KD = 768; }
  else if (idx < 163840)  { in = Wv;  outb = Wfv; local = idx - 98304;  P = 128; KD = 512; }
  else if (idx < 212992)  { in = Wa;  outb = Wfa; local = idx - 163840; P = 128; KD = 384; }
  else if (idx < 278528)  { in = Wf2; outb = WF2; local = idx - 212992; P = 256; KD = 256; }
  else return;
  const int c = local / KD, k = local - c*KD;
  outb[fragIdx1(c, k, P)] = (half_t)(in[local] * 256.f);
}

// ===== proj: B-panel phase LDS (32KB, 4 chunks/phase), depth-4 reg-A, split-A x f16-B =====
template<int KD>
DI void proj_body(const float* __restrict__ X, const half_t* __restrict__ BF,
                  const float* __restrict__ bias,
                  const float* __restrict__ lnw, const float* __restrict__ lnb,
                  const float* __restrict__ Ghat, float* __restrict__ tva,
                  float* __restrict__ zpart, int row0, int colOff, int srcIdx,
                  f32x4* Bs)
{
  const int tid = threadIdx.x;
  const int lane = tid & 63, wid = tid >> 6;
  const int l15 = lane & 15, l4 = lane >> 4;
  constexpr int NT = KD >> 5;
  constexpr int NM = NT >> 2;      // 6 / 4 / 3 phases of 4 K-chunks
  const int r0 = row0 + wid*32;

  const float* xr0 = X + (size_t)(r0 + l15)*KD + l4*8;
  const float* xr1 = X + (size_t)(r0 + 16 + l15)*KD + l4*8;

  f32x4 A0[4], A1[4], A2[4], A3[4];
  auto LA = [&](int t, f32x4 (&a)[4]) {
    const int tc = (t < NT) ? t : NT - 1;
    const f32x4* p0 = reinterpret_cast<const f32x4*>(xr0 + tc*32);
    const f32x4* p1 = reinterpret_cast<const f32x4*>(xr1 + tc*32);
    a[0] = p0[0]; a[1] = p0[1]; a[2] = p1[0]; a[3] = p1[1];
  };
  auto SPLIT = [&](f32x4 (&a)[4], f16x8& h0, f16x8& l0, f16x8& h1, f16x8& l1) {
#pragma unroll
    for (int j = 0; j < 4; ++j) {
      half_t x;
      x = (half_t)a[0][j]; h0[j]   = x; l0[j]   = (half_t)(a[0][j] - (float)x);
      x = (half_t)a[1][j]; h0[j+4] = x; l0[j+4] = (half_t)(a[1][j] - (float)x);
      x = (half_t)a[2][j]; h1[j]   = x; l1[j]   = (half_t)(a[2][j] - (float)x);
      x = (half_t)a[3][j]; h1[j+4] = x; l1[j+4] = (half_t)(a[3][j] - (float)x);
    }
  };

  f32x4 acc[2][8];
#pragma unroll
  for (int rg = 0; rg < 2; ++rg)
#pragma unroll
    for (int fn = 0; fn < 8; ++fn) acc[rg][fn] = f32x4{0.f, 0.f, 0.f, 0.f};

  LA(0, A0); LA(1, A1); LA(2, A2); LA(3, A3);

#define PROJ_CHUNK(ABUF, TL)                                              \
  {                                                                       \
    f16x8 h0, l0, h1, l1;                                                 \
    SPLIT(ABUF, h0, l0, h1, l1);                                          \
    LA(tb + 4 + (TL), ABUF);                                              \
    _Pragma("unroll")                                                     \
    for (int fn = 0; fn < 8; ++fn) {                                      \
      f16x8 b = asH(Bs[((TL)*8 + fn)*64 + lane]);                         \
      acc[0][fn] = MFMA16(h0, b, acc[0][fn], 0, 0, 0);                    \
      acc[0][fn] = MFMA16(l0, b, acc[0][fn], 0, 0, 0);                    \
      acc[1][fn] = MFMA16(h1, b, acc[1][fn], 0, 0, 0);                    \
      acc[1][fn] = MFMA16(l1, b, acc[1][fn], 0, 0, 0);                    \
    }                                                                     \
  }

  for (int m = 0; m < NM; ++m) {
    __syncthreads();                           // all waves done with previous B panel
    const half_t* s = BF + (size_t)m*16384;    // 32KB phase slab, linear frag-major
#pragma unroll
    for (int i = 0; i < 8; ++i)
      gl16(s + i*2048 + tid*8, (char*)Bs + i*4096 + wid*1024);
    __syncthreads();                           // B panel visible
    const int tb = m*4;
    PROJ_CHUNK(A0, 0)
    PROJ_CHUNK(A1, 1)
    PROJ_CHUNK(A2, 2)
    PROJ_CHUNK(A3, 3)
  }
#undef PROJ_CHUNK

  // epilogue: descale+bias, LN over 128 cols (16-lane shfl), ReLU, store tva, z-partials
  float bc[8], lw[8], lb[8], gh[6][8];
#pragma unroll
  for (int fn = 0; fn < 8; ++fn) {
    const int c = fn*16 + l15;
    bc[fn] = bias[c]; lw[fn] = lnw[c]; lb[fn] = lnb[c];
#pragma unroll
    for (int j = 0; j < 6; ++j) gh[j][fn] = Ghat[j*384 + colOff + c];
  }
#pragma unroll
  for (int rg = 0; rg < 2; ++rg) {
#pragma unroll
    for (int r = 0; r < 4; ++r) {
      float h[8];
      float s = 0.f, q2 = 0.f;
#pragma unroll
      for (int fn = 0; fn < 8; ++fn) {
        h[fn] = acc[rg][fn][r]*(1.f/256.f) + bc[fn];
        s += h[fn]; q2 = fmaf(h[fn], h[fn], q2);
      }
#pragma unroll
      for (int m = 1; m <= 8; m <<= 1) { s += __shfl_xor(s, m); q2 += __shfl_xor(q2, m); }
      const float mean = s*(1.f/128.f);
      const float var  = q2*(1.f/128.f) - mean*mean;
      const float rstd = rsqrtf(var + 1e-5f);
      float o[8];
#pragma unroll
      for (int fn = 0; fn < 8; ++fn)
        o[fn] = fmaxf(fmaf((h[fn] - mean)*rstd, lw[fn], lb[fn]), 0.f);
      const int grow = r0 + rg*16 + l4*4 + r;
      float* tp = tva + (size_t)grow*384 + colOff;
#pragma unroll
      for (int fn = 0; fn < 8; ++fn) tp[fn*16 + l15] = o[fn];
      float s6[6];
#pragma unroll
      for (int j = 0; j < 6; ++j) {
        float z = 0.f;
#pragma unroll
        for (int fn = 0; fn < 8; ++fn) z = fmaf(o[fn], gh[j][fn], z);
#pragma unroll
        for (int m = 1; m <= 8; m <<= 1) z += __shfl_xor(z, m);
        s6[j] = z;
      }
#pragma unroll
      for (int j = 0; j < 6; ++j)
        if (l15 == j) zpart[(size_t)(srcIdx*PB + grow)*6 + j] = s6[j];
    }
  }
}

__global__ __launch_bounds__(256, 4)
void k_proj(const float* __restrict__ xt, const float* __restrict__ xv,
            const float* __restrict__ xa, const half_t* __restrict__ Wft,
            const half_t* __restrict__ Wfv, const half_t* __restrict__ Wfa,
            const float* __restrict__ bt, const float* __restrict__ lnwt, const float* __restrict__ lnbt,
            const float* __restrict__ bvp, const float* __restrict__ lnwv, const float* __restrict__ lnbv,
            const float* __restrict__ bap, const float* __restrict__ lnwa, const float* __restrict__ lnba,
            const float* __restrict__ Ghat, float* __restrict__ tva, float* __restrict__ zpart)
{
  __shared__ f32x4 Bs[2048];                   // 32KB B phase panel
  const int src = blockIdx.y;
  const int row0 = blockIdx.x * 128;
  if (src == 0)
    proj_body<768>(xt, Wft, bt, lnwt, lnbt, Ghat, tva, zpart, row0, 0, 0, Bs);
  else if (src == 1)
    proj_body<512>(xv, Wfv, bvp, lnwv, lnbv, Ghat, tva, zpart, row0, 128, 1, Bs);
  else
    proj_body<384>(xa, Wfa, bap, lnwa, lnba, Ghat, tva, zpart, row0, 256, 2, Bs);
}

// gate combine
__global__ void k_gate2(const float* __restrict__ zp, const float* __restrict__ svec,
                        float* __restrict__ g)
{
  const int r = blockIdx.x*256 + threadIdx.x;
  float z[6];
#pragma unroll
  for (int j = 0; j < 6; ++j)
    z[j] = zp[(size_t)r*6 + j] + zp[(size_t)(PB + r)*6 + j] + zp[(size_t)(2*PB + r)*6 + j] + svec[j];
  float mx = z[0];
#pragma unroll
  for (int j = 1; j < 6; ++j) mx = fmaxf(mx, z[j]);
  float e[6], s = 0.f;
#pragma unroll
  for (int j = 0; j < 6; ++j) { e[j] = expf(z[j] - mx); s += e[j]; }
  const float inv = 1.f / s;
#pragma unroll
  for (int j = 0; j < 6; ++j) g[(size_t)r*6 + j] = e[j]*inv;
}

// ================= f1: phase LDS B, split gated A, K chunks 0..24 (+cvec tail) =================
__global__ __launch_bounds__(256, 3)
void k_f1(const float* __restrict__ tva, const half_t* __restrict__ Nf,
          const float* __restrict__ gbuf, const float* __restrict__ bias,
          half_t* __restrict__ h1h)
{
  __shared__ f32x4 Bs[2048];
  const int tid = threadIdx.x;
  const int row0 = blockIdx.x * 128;
  const int colOff = blockIdx.y * 128;
  const int fn0 = colOff >> 4;
  const int lane = tid & 63, wid = tid >> 6;
  const int l15 = lane & 15, l4 = lane >> 4;
  const int r0 = row0 + wid*32;

  const float* ar0 = tva + (size_t)(r0 + l15)*384 + l4*8;
  const float* ar1 = tva + (size_t)(r0 + 16 + l15)*384 + l4*8;

  f32x4 a0[4], a1[4];
  auto LA = [&](int t, f32x4 (&a)[4]) {
    const int tc = (t < 24) ? t : 23;
    const int koff = ((0x102021 >> ((tc >> 2)*4)) & 3)*128 + (tc & 3)*32;
    const f32x4* p0 = reinterpret_cast<const f32x4*>(ar0 + koff);
    const f32x4* p1 = reinterpret_cast<const f32x4*>(ar1 + koff);
    a[0] = p0[0]; a[1] = p0[1]; a[2] = p1[0]; a[3] = p1[1];
  };
  auto SPLITG = [&](f32x4 (&a)[4], float s0, float s1,
                    f16x8& h0, f16x8& l0, f16x8& h1, f16x8& l1) {
#pragma unroll
    for (int j = 0; j < 4; ++j) {
      float v; half_t x;
      v = a[0][j]*s0; x = (half_t)v; h0[j]   = x; l0[j]   = (half_t)(v - (float)x);
      v = a[1][j]*s0; x = (half_t)v; h0[j+4] = x; l0[j+4] = (half_t)(v - (float)x);
      v = a[2][j]*s1; x = (half_t)v; h1[j]   = x; l1[j]   = (half_t)(v - (float)x);
      v = a[3][j]*s1; x = (half_t)v; h1[j+4] = x; l1[j+4] = (half_t)(v - (float)x);
    }
  };

  f32x4 acc[2][8];
#pragma unroll
  for (int rg = 0; rg < 2; ++rg)
#pragma unroll
    for (int fn = 0; fn < 8; ++fn) acc[rg][fn] = f32x4{0.f, 0.f, 0.f, 0.f};

  LA(0, a0); LA(1, a1);

  for (int q = 0; q < 6; ++q) {                 // 6 phases x 4 chunks = chunks 0..23
    const float sq0 = gbuf[(size_t)(r0 + l15)*6 + q] * 16.f;
    const float sq1 = gbuf[(size_t)(r0 + 16 + l15)*6 + q] * 16.f;
    __syncthreads();
#pragma unroll
    for (int p = 0; p < 4; ++p) {
      const half_t* sp = Nf + ((size_t)(q*4 + p)*16 + fn0)*512;
#pragma unroll
      for (int i = 0; i < 2; ++i)
        gl16(sp + i*2048 + tid*8, (char*)Bs + p*8192 + i*4096 + wid*1024);
    }
    __syncthreads();
#pragma unroll
    for (int p = 0; p < 4; ++p) {
      const int t = q*4 + p;
      f16x8 h0, l0, h1, l1;
      if (p & 1) { SPLITG(a1, sq0, sq1, h0, l0, h1, l1); LA(t + 2, a1); }
      else       { SPLITG(a0, sq0, sq1, h0, l0, h1, l1); LA(t + 2, a0); }
#pragma unroll
      for (int fn = 0; fn < 8; ++fn) {
        f16x8 b = asH(Bs[(p*8 + fn)*64 + lane]);
        acc[0][fn] = MFMA16(h0, b, acc[0][fn], 0, 0, 0);
        acc[0][fn] = MFMA16(l0, b, acc[0][fn], 0, 0, 0);
        acc[1][fn] = MFMA16(h1, b, acc[1][fn], 0, 0, 0);
        acc[1][fn] = MFMA16(l1, b, acc[1][fn], 0, 0, 0);
      }
    }
  }

  // tail chunk 24: A = gate one-hot (cols 768..773 = cvec)
  __syncthreads();
  {
    const half_t* sT = Nf + ((size_t)24*16 + fn0)*512;
#pragma unroll
    for (int i = 0; i < 2; ++i)
      gl16(sT + i*2048 + tid*8, (char*)Bs + i*4096 + wid*1024);
  }
  __syncthreads();
  {
    f16x8 h0, h1;
#pragma unroll
    for (int j = 0; j < 8; ++j) {
      h0[j] = (l4 == 0 && j < 6) ? (half_t)(gbuf[(size_t)(r0 + l15)*6 + j]*16.f) : (half_t)0.f;
      h1[j] = (l4 == 0 && j < 6) ? (half_t)(gbuf[(size_t)(r0 + 16 + l15)*6 + j]*16.f) : (half_t)0.f;
    }
#pragma unroll
    for (int fn = 0; fn < 8; ++fn) {
      f16x8 b = asH(Bs[fn*64 + lane]);
      acc[0][fn] = MFMA16(h0, b, acc[0][fn], 0, 0, 0);
      acc[1][fn] = MFMA16(h1, b, acc[1][fn], 0, 0, 0);
    }
  }

  float bc[8];
#pragma unroll
  for (int fn = 0; fn < 8; ++fn) bc[fn] = bias[colOff + fn*16 + l15];
#pragma unroll
  for (int rg = 0; rg < 2; ++rg)
#pragma unroll
    for (int fn = 0; fn < 8; ++fn)
#pragma unroll
      for (int r = 0; r < 4; ++r) {
        float v = acc[rg][fn][r]*(1.f/65536.f) + bc[fn];
        v = fmaxf(v, 0.f) * 256.f;                    // pre-scale h1 for f16
        const int grow = r0 + rg*16 + l4*4 + r;
        h1h[(size_t)grow*256 + colOff + fn*16 + l15] = (half_t)v;
      }
}

// ================= f2: phase LDS B, f16 A, K=256 (2 phases), fused head =================
__global__ __launch_bounds__(256, 3)
void k_f2(const half_t* __restrict__ h1h, const half_t* __restrict__ WF,
          const float* __restrict__ bias, const float* __restrict__ Wout,
          float* __restrict__ part)
{
  __shared__ f32x4 Bs[2048];
  const int tid = threadIdx.x;
  const int row0 = blockIdx.x * 128;
  const int colOff = blockIdx.y * 128;
  const int fn0 = colOff >> 4;
  const int lane = tid & 63, wid = tid >> 6;
  const int l15 = lane & 15, l4 = lane >> 4;
  const int r0 = row0 + wid*32;

  const half_t* hr0 = h1h + (size_t)(r0 + l15)*256 + l4*8;
  const half_t* hr1 = h1h + (size_t)(r0 + 16 + l15)*256 + l4*8;

  f16x8 a0[2], a1[2];
  auto LA = [&](int t, f16x8 (&a)[2]) {
    const int tc = (t < 8) ? t : 7;
    a[0] = *reinterpret_cast<const f16x8*>(hr0 + tc*32);
    a[1] = *reinterpret_cast<const f16x8*>(hr1 + tc*32);
  };

  f32x4 acc[2][8];
#pragma unroll
  for (int rg = 0; rg < 2; ++rg)
#pragma unroll
    for (int fn = 0; fn < 8; ++fn) acc[rg][fn] = f32x4{0.f, 0.f, 0.f, 0.f};

  LA(0, a0); LA(1, a1);

  for (int q = 0; q < 2; ++q) {
    __syncthreads();
#pragma unroll
    for (int p = 0; p < 4; ++p) {
      const half_t* sp = WF + ((size_t)(q*4 + p)*16 + fn0)*512;
#pragma unroll
      for (int i = 0; i < 2; ++i)
        gl16(sp + i*2048 + tid*8, (char*)Bs + p*8192 + i*4096 + wid*1024);
    }
    __syncthreads();
#pragma unroll
    for (int p = 0; p < 4; ++p) {
      const int t = q*4 + p;
      f16x8 h0, h1;
      if (p & 1) { h0 = a1[0]; h1 = a1[1]; LA(t + 2, a1); }
      else       { h0 = a0[0]; h1 = a0[1]; LA(t + 2, a0); }
#pragma unroll
      for (int fn = 0; fn < 8; ++fn) {
        f16x8 b = asH(Bs[(p*8 + fn)*64 + lane]);
        acc[0][fn] = MFMA16(h0, b, acc[0][fn], 0, 0, 0);
        acc[1][fn] = MFMA16(h1, b, acc[1][fn], 0, 0, 0);
      }
    }
  }

  // epilogue: relu(h2), partial dot with Wout over this block's 128 cols
  float bc[8], w0[8], w1[8];
#pragma unroll
  for (int fn = 0; fn < 8; ++fn) {
    const int c = colOff + fn*16 + l15;
    bc[fn] = bias[c]; w0[fn] = Wout[c]; w1[fn] = Wout[256 + c];
  }
#pragma unroll
  for (int rg = 0; rg < 2; ++rg)
#pragma unroll
    for (int r = 0; r < 4; ++r) {
      float s0 = 0.f, s1 = 0.f;
#pragma unroll
      for (int fn = 0; fn < 8; ++fn) {
        float hv = fmaxf(acc[rg][fn][r]*(1.f/65536.f) + bc[fn], 0.f);
        s0 = fmaf(hv, w0[fn], s0);
        s1 = fmaf(hv, w1[fn], s1);
      }
#pragma unroll
      for (int m = 1; m <= 8; m <<= 1) { s0 += __shfl_xor(s0, m); s1 += __shfl_xor(s1, m); }
      if (l15 == rg*4 + r) {
        const int grow = r0 + rg*16 + l4*4 + r;
        float* pp = part + ((size_t)blockIdx.y*PB + grow)*2;
        pp[0] = s0; pp[1] = s1;
      }
    }
}

__global__ void k_comb(const float* __restrict__ part, const float* __restrict__ bout,
                       float* __restrict__ out)
{
  const int id = blockIdx.x*256 + threadIdx.x;
  const int j = id & 1;
  float s = bout[j];
#pragma unroll
  for (int s2 = 0; s2 < 2; ++s2) s += part[(size_t)s2*PB*2 + id];
  out[id] = s;
}

} // namespace

extern "C" void kernel_launch(void* const* d_in, const int* in_sizes, int n_in,
                              void* d_out, int out_size, void* d_ws, size_t ws_size,
                              hipStream_t stream)
{
  const float* xt   = (const float*)d_in[0];
  const float* xv   = (const float*)d_in[1];
  const float* xa   = (const float*)d_in[2];
  const float* Wt   = (const float*)d_in[3];
  const float* bt   = (const float*)d_in[4];
  const float* lnwt = (const float*)d_in[5];
  const float* lnbt = (const float*)d_in[6];
  const float* Wv   = (const float*)d_in[7];
  const float* bv   = (const float*)d_in[8];
  const float* lnwv = (const float*)d_in[9];
  const float* lnbv = (const float*)d_in[10];
  const float* Wa   = (const float*)d_in[11];
  const float* ba   = (const float*)d_in[12];
  const float* lnwa = (const float*)d_in[13];
  const float* lnba = (const float*)d_in[14];
  const float* Wqkv = (const float*)d_in[15];
  const float* bqkv = (const float*)d_in[16];
  const float* Wo   = (const float*)d_in[17];
  const float* bo   = (const float*)d_in[18];
  const float* Wg   = (const float*)d_in[19];
  const float* bg   = (const float*)d_in[20];
  const float* Wf1  = (const float*)d_in[21];
  const float* bf1  = (const float*)d_in[22];
  const float* Wf2  = (const float*)d_in[23];
  const float* bf2  = (const float*)d_in[24];
  const float* Woutp= (const float*)d_in[25];
  const float* boutp= (const float*)d_in[26];
  float* out = (float*)d_out;

  float* ws   = (float*)d_ws;
  float* tva  = ws;                              // PB*384 f32
  float* g    = tva  + (size_t)PB*384;           // PB*6
  float* h1pf = g    + (size_t)PB*6;             // PB*128 f32 (h1 halfs PB*256)
  float* M    = h1pf + (size_t)PB*128;           // 98304
  float* beff = M    + 98304;                    // 768
  half_t* Wft = (half_t*)(beff + 768);           // 98304 h (6 panels x 16384)
  half_t* Wfv = Wft + 98304;                     // 65536 h (4 panels)
  half_t* Wfa = Wfv + 65536;                     // 49152 h (3 panels)
  half_t* Nf  = Wfa + 49152;                     // 204800 h (25 chunks x 16 x 512)
  half_t* WF2 = Nf + 204800;                     // 65536 h
  float* Ghat = (float*)(WF2 + 65536);           // 2304
  float* svec = Ghat + 2304;                     // 8
  half_t* h1h = (half_t*)h1pf;
  float* zpart = h1pf;                           // 3*PB*6, dead before f1 writes h1h
  float* part  = tva;                            // 2*PB*2, tva dead before f2

  // weight composition + fragment-major single-plane splits (merged launches)
  k_weff<<<768, 128, 0, stream>>>(Wqkv, bqkv, Wo, bo, M, beff);
  k_nbig2<<<1536, 128, 0, stream>>>(Wf1, M, beff, Nf);
  k_gsv<<<24, 128, 0, stream>>>(M, Wg, beff, bg, Ghat, svec);
  k_splitall<<<1088, 256, 0, stream>>>(Wt, Wv, Wa, Wf2, Wft, Wfv, Wfa, WF2);

  // merged projections (fused LN+ReLU+gate-partials)
  k_proj<<<dim3(256, 3), 256, 0, stream>>>(xt, xv, xa, Wft, Wfv, Wfa,
                                           bt, lnwt, lnbt, bv, lnwv, lnbv, ba, lnwa, lnba,
                                           Ghat, tva, zpart);

  // gate
  k_gate2<<<PB/256, 256, 0, stream>>>(zpart, svec, g);

  // f1 (gated fused branch+f1, cvec folded), f2 (fused head partials), combine
  k_f1<<<dim3(256, 2), 256, 0, stream>>>(tva, Nf, g, bf1, h1h);
  k_f2<<<dim3(256, 2), 256, 0, stream>>>(h1h, WF2, bf2, Woutp, part);
  k_comb<<<256, 256, 0, stream>>>(part, boutp, out);
}

// Round 14
// 163.216 us; speedup vs baseline: 1.6205x; 1.6205x over previous
//
#include <hip/hip_runtime.h>
#include <math.h>

#define DI __device__ __forceinline__

namespace {

constexpr int PB = 32768;   // batch

typedef _Float16 half_t;
typedef float f32x4 __attribute__((ext_vector_type(4)));
typedef _Float16 f16x8 __attribute__((ext_vector_type(8)));

#define MFMA16 __builtin_amdgcn_mfma_f32_16x16x32_f16

DI void gl16(const void* g, void* l) {
  __builtin_amdgcn_global_load_lds((const __attribute__((address_space(1))) void*)g,
                                   (__attribute__((address_space(3))) void*)l, 16, 0, 0);
}
DI f16x8 asH(f32x4 v) { return __builtin_bit_cast(f16x8, v); }

// single-plane fragment-major index:
// chunk = (k>>5)*(P/16) + (c>>4); within chunk: ((k>>3)&3)*128 + (c&15)*8 + (k&7)
DI size_t fragIdx1(int c, int k, int P) {
  return (size_t)((k >> 5)*(P >> 4) + (c >> 4))*512
       + ((k >> 3) & 3)*128 + (c & 15)*8 + (k & 7);
}

// ---------------- precompute kernels (all tiny) ----------------

__global__ void k_weff(const float* __restrict__ Wqkv, const float* __restrict__ bqkv,
                       const float* __restrict__ Wo, const float* __restrict__ bo,
                       float* __restrict__ M, float* __restrict__ beff)
{
  const int i = blockIdx.x >> 7;
  const int c = blockIdx.x & 127;
  const int k = threadIdx.x;
  const float* wo_row = Wo + (size_t)(i*128 + c)*128;
  const float* wv = Wqkv + (size_t)(i*384 + 256)*128;
  float acc = 0.f;
#pragma unroll 4
  for (int j = 0; j < 128; ++j)
    acc = fmaf(wo_row[j], wv[j*128 + k], acc);
  M[(size_t)(i*128 + c)*128 + k] = acc;

  __shared__ float red[128];
  const float* bv = bqkv + i*384 + 256;
  red[k] = wo_row[k] * bv[k];
  __syncthreads();
  for (int s = 64; s > 0; s >>= 1) {
    if (k < s) red[k] += red[k + s];
    __syncthreads();
  }
  if (k == 0) beff[i*128 + c] = red[0] + bo[i*128 + c];
}

// N fragments (P=256, K chunks 0..24): 4096*(Wf1·M); k=768+i col = 4096*cvec_i; pad zero
__global__ void k_nbig2(const float* __restrict__ Wf1, const float* __restrict__ M,
                        const float* __restrict__ beff, half_t* __restrict__ Nf)
{
  const int i = blockIdx.x >> 8;
  const int c = blockIdx.x & 255;
  const int k = threadIdx.x;
  const float* w_row = Wf1 + (size_t)c*768 + i*128;
  const float* Mi = M + (size_t)i*128*128;
  float acc = 0.f;
#pragma unroll 4
  for (int j = 0; j < 128; ++j)
    acc = fmaf(w_row[j], Mi[j*128 + k], acc);
  Nf[fragIdx1(c, i*128 + k, 256)] = (half_t)(acc * 4096.f);

  __shared__ float red[128];
  red[k] = w_row[k] * beff[i*128 + k];
  __syncthreads();
  for (int s = 64; s > 0; s >>= 1) {
    if (k < s) red[k] += red[k + s];
    __syncthreads();
  }
  if (k == 0)
    Nf[fragIdx1(c, 768 + i, 256)] = (half_t)(red[0] * 4096.f);
  if (i == 0 && k < 26)
    Nf[fragIdx1(c, 774 + k, 256)] = (half_t)0.f;
}

// merged ghat (blocks 0..17) + svec (blocks 18..23)
__global__ void k_gsv(const float* __restrict__ M, const float* __restrict__ Wg,
                      const float* __restrict__ beff, const float* __restrict__ bg,
                      float* __restrict__ Ghat, float* __restrict__ svec)
{
  const int bid = blockIdx.x;
  const int k = threadIdx.x;
  if (bid < 18) {
    const int j = bid / 3;
    const int src = bid % 3;
    int i0, i1;
    if (src == 0)      { i0 = 2; i1 = 4; }
    else if (src == 1) { i0 = 0; i1 = 5; }
    else               { i0 = 1; i1 = 3; }
    float acc = 0.f;
    for (int t = 0; t < 2; ++t) {
      const int i = t ? i1 : i0;
      const float* Mi = M + (size_t)i*128*128;
      const float* wg = Wg + j*768 + i*128;
#pragma unroll 4
      for (int c = 0; c < 128; ++c)
        acc = fmaf(Mi[c*128 + k], wg[c], acc);
    }
    Ghat[j*384 + src*128 + k] = acc;
  } else {
    const int j = bid - 18;
    float p = 0.f;
#pragma unroll
    for (int i = 0; i < 6; ++i)
      p = fmaf(beff[i*128 + k], Wg[j*768 + i*128 + k], p);
    __shared__ float red[128];
    red[k] = p;
    __syncthreads();
    for (int s = 64; s > 0; s >>= 1) {
      if (k < s) red[k] += red[k + s];
      __syncthreads();
    }
    if (k == 0) svec[j] = red[0] + bg[j];
  }
}

// merged fp32->f16 fragment-major split for all four weight tensors
__global__ void k_splitall(const float* __restrict__ Wt, const float* __restrict__ Wv,
                           const float* __restrict__ Wa, const float* __restrict__ Wf2,
                           half_t* __restrict__ Wft, half_t* __restrict__ Wfv,
                           half_t* __restrict__ Wfa, half_t* __restrict__ WF2)
{
  const int idx = blockIdx.x*256 + threadIdx.x;
  const float* in; half_t* outb; int local, P, KD;
  if (idx < 98304)        { in = Wt;  outb = Wft; local = idx;          P = 128; KD = 768; }
  else if (idx < 163840)  { in = Wv;  outb = Wfv; local = idx - 98304;  P = 128; KD = 512; }
  else if (idx < 212992)  { in = Wa;  outb = Wfa; local = idx - 163840; P = 128; KD = 384; }
  else if (idx < 278528)  { in = Wf2; outb = WF2; local = idx - 212992; P = 256; KD = 256; }
  else return;
  const int c = local / KD, k = local - c*KD;
  outb[fragIdx1(c, k, P)] = (half_t)(in[local] * 256.f);
}

// ===== proj: contiguous-A LDS staging (256B runs, swizzled), phase = 2 K-chunks =====
template<int KD>
DI void proj_body(const float* __restrict__ X, const half_t* __restrict__ BF,
                  const float* __restrict__ bias,
                  const float* __restrict__ lnw, const float* __restrict__ lnb,
                  const float* __restrict__ Ghat, float* __restrict__ tva,
                  float* __restrict__ zpart, int row0, int colOff, int srcIdx,
                  f32x4* As, f32x4* Bs)
{
  const int tid = threadIdx.x;
  const int lane = tid & 63, wid = tid >> 6;
  const int l15 = lane & 15, l4 = lane >> 4;
  constexpr int NPH = KD >> 6;          // 64 k-floats (256B) per row per phase
  const int r0 = row0 + wid*32;

  f32x4 acc[2][8];
#pragma unroll
  for (int rg = 0; rg < 2; ++rg)
#pragma unroll
    for (int fn = 0; fn < 8; ++fn) acc[rg][fn] = f32x4{0.f, 0.f, 0.f, 0.f};

  for (int q = 0; q < NPH; ++q) {
    __syncthreads();                    // previous phase's panels consumed
    // stage A: 32KB, 256B-contiguous-per-row runs, source pre-swizzled per lane
#pragma unroll
    for (int i = 0; i < 8; ++i) {
      const int row_l = wid*32 + i*4 + (lane >> 4);
      const char* src = (const char*)X + (size_t)(row0 + row_l)*KD*4 + q*256
                      + (((lane & 15)*16) ^ ((row_l & 7) << 5));
      gl16(src, (char*)As + wid*8192 + i*1024);
    }
    // stage B: 16KB (chunks 2q, 2q+1), linear frag-major
    {
      const half_t* s = BF + (size_t)q*8192;
#pragma unroll
      for (int i = 0; i < 4; ++i)
        gl16(s + i*2048 + tid*8, (char*)Bs + i*4096 + wid*1024);
    }
    __syncthreads();                    // panels visible
#pragma unroll
    for (int tb = 0; tb < 2; ++tb) {
      // A fragments from swizzled LDS (2-way bank alias = free)
      f16x8 h0, l0, h1, l1;
#pragma unroll
      for (int rg = 0; rg < 2; ++rg) {
        const int row_l = wid*32 + rg*16 + l15;
        const int off = row_l*256 + ((tb*128 + l4*32) ^ ((row_l & 7) << 5));
        f32x4 v0 = *reinterpret_cast<const f32x4*>((const char*)As + off);
        f32x4 v1 = *reinterpret_cast<const f32x4*>((const char*)As + off + 16);
#pragma unroll
        for (int j = 0; j < 4; ++j) {
          half_t x;
          if (rg == 0) {
            x = (half_t)v0[j]; h0[j]   = x; l0[j]   = (half_t)(v0[j] - (float)x);
            x = (half_t)v1[j]; h0[j+4] = x; l0[j+4] = (half_t)(v1[j] - (float)x);
          } else {
            x = (half_t)v0[j]; h1[j]   = x; l1[j]   = (half_t)(v0[j] - (float)x);
            x = (half_t)v1[j]; h1[j+4] = x; l1[j+4] = (half_t)(v1[j] - (float)x);
          }
        }
      }
#pragma unroll
      for (int fn = 0; fn < 8; ++fn) {
        f16x8 b = asH(Bs[(tb*8 + fn)*64 + lane]);
        acc[0][fn] = MFMA16(h0, b, acc[0][fn], 0, 0, 0);
        acc[0][fn] = MFMA16(l0, b, acc[0][fn], 0, 0, 0);
        acc[1][fn] = MFMA16(h1, b, acc[1][fn], 0, 0, 0);
        acc[1][fn] = MFMA16(l1, b, acc[1][fn], 0, 0, 0);
      }
    }
  }

  // epilogue: descale+bias, LN over 128 cols (16-lane shfl), ReLU, store tva, z-partials
  float bc[8], lw[8], lb[8], gh[6][8];
#pragma unroll
  for (int fn = 0; fn < 8; ++fn) {
    const int c = fn*16 + l15;
    bc[fn] = bias[c]; lw[fn] = lnw[c]; lb[fn] = lnb[c];
#pragma unroll
    for (int j = 0; j < 6; ++j) gh[j][fn] = Ghat[j*384 + colOff + c];
  }
#pragma unroll
  for (int rg = 0; rg < 2; ++rg) {
#pragma unroll
    for (int r = 0; r < 4; ++r) {
      float h[8];
      float s = 0.f, q2 = 0.f;
#pragma unroll
      for (int fn = 0; fn < 8; ++fn) {
        h[fn] = acc[rg][fn][r]*(1.f/256.f) + bc[fn];
        s += h[fn]; q2 = fmaf(h[fn], h[fn], q2);
      }
#pragma unroll
      for (int m = 1; m <= 8; m <<= 1) { s += __shfl_xor(s, m); q2 += __shfl_xor(q2, m); }
      const float mean = s*(1.f/128.f);
      const float var  = q2*(1.f/128.f) - mean*mean;
      const float rstd = rsqrtf(var + 1e-5f);
      float o[8];
#pragma unroll
      for (int fn = 0; fn < 8; ++fn)
        o[fn] = fmaxf(fmaf((h[fn] - mean)*rstd, lw[fn], lb[fn]), 0.f);
      const int grow = r0 + rg*16 + l4*4 + r;
      float* tp = tva + (size_t)grow*384 + colOff;
#pragma unroll
      for (int fn = 0; fn < 8; ++fn) tp[fn*16 + l15] = o[fn];
      float s6[6];
#pragma unroll
      for (int j = 0; j < 6; ++j) {
        float z = 0.f;
#pragma unroll
        for (int fn = 0; fn < 8; ++fn) z = fmaf(o[fn], gh[j][fn], z);
#pragma unroll
        for (int m = 1; m <= 8; m <<= 1) z += __shfl_xor(z, m);
        s6[j] = z;
      }
#pragma unroll
      for (int j = 0; j < 6; ++j)
        if (l15 == j) zpart[(size_t)(srcIdx*PB + grow)*6 + j] = s6[j];
    }
  }
}

__global__ __launch_bounds__(256, 3)
void k_proj(const float* __restrict__ xt, const float* __restrict__ xv,
            const float* __restrict__ xa, const half_t* __restrict__ Wft,
            const half_t* __restrict__ Wfv, const half_t* __restrict__ Wfa,
            const float* __restrict__ bt, const float* __restrict__ lnwt, const float* __restrict__ lnbt,
            const float* __restrict__ bvp, const float* __restrict__ lnwv, const float* __restrict__ lnbv,
            const float* __restrict__ bap, const float* __restrict__ lnwa, const float* __restrict__ lnba,
            const float* __restrict__ Ghat, float* __restrict__ tva, float* __restrict__ zpart)
{
  __shared__ f32x4 As[2048];                   // 32KB A phase panel (swizzled rows)
  __shared__ f32x4 Bs[1024];                   // 16KB B phase panel
  const int src = blockIdx.y;
  const int row0 = blockIdx.x * 128;
  if (src == 0)
    proj_body<768>(xt, Wft, bt, lnwt, lnbt, Ghat, tva, zpart, row0, 0, 0, As, Bs);
  else if (src == 1)
    proj_body<512>(xv, Wfv, bvp, lnwv, lnbv, Ghat, tva, zpart, row0, 128, 1, As, Bs);
  else
    proj_body<384>(xa, Wfa, bap, lnwa, lnba, Ghat, tva, zpart, row0, 256, 2, As, Bs);
}

// gate combine
__global__ void k_gate2(const float* __restrict__ zp, const float* __restrict__ svec,
                        float* __restrict__ g)
{
  const int r = blockIdx.x*256 + threadIdx.x;
  float z[6];
#pragma unroll
  for (int j = 0; j < 6; ++j)
    z[j] = zp[(size_t)r*6 + j] + zp[(size_t)(PB + r)*6 + j] + zp[(size_t)(2*PB + r)*6 + j] + svec[j];
  float mx = z[0];
#pragma unroll
  for (int j = 1; j < 6; ++j) mx = fmaxf(mx, z[j]);
  float e[6], s = 0.f;
#pragma unroll
  for (int j = 0; j < 6; ++j) { e[j] = expf(z[j] - mx); s += e[j]; }
  const float inv = 1.f / s;
#pragma unroll
  for (int j = 0; j < 6; ++j) g[(size_t)r*6 + j] = e[j]*inv;
}

// ================= f1: phase LDS B, split gated A, K chunks 0..24 (+cvec tail) =================
__global__ __launch_bounds__(256, 3)
void k_f1(const float* __restrict__ tva, const half_t* __restrict__ Nf,
          const float* __restrict__ gbuf, const float* __restrict__ bias,
          half_t* __restrict__ h1h)
{
  __shared__ f32x4 Bs[2048];
  const int tid = threadIdx.x;
  const int row0 = blockIdx.x * 128;
  const int colOff = blockIdx.y * 128;
  const int fn0 = colOff >> 4;
  const int lane = tid & 63, wid = tid >> 6;
  const int l15 = lane & 15, l4 = lane >> 4;
  const int r0 = row0 + wid*32;

  const float* ar0 = tva + (size_t)(r0 + l15)*384 + l4*8;
  const float* ar1 = tva + (size_t)(r0 + 16 + l15)*384 + l4*8;

  f32x4 a0[4], a1[4];
  auto LA = [&](int t, f32x4 (&a)[4]) {
    const int tc = (t < 24) ? t : 23;
    const int koff = ((0x102021 >> ((tc >> 2)*4)) & 3)*128 + (tc & 3)*32;
    const f32x4* p0 = reinterpret_cast<const f32x4*>(ar0 + koff);
    const f32x4* p1 = reinterpret_cast<const f32x4*>(ar1 + koff);
    a[0] = p0[0]; a[1] = p0[1]; a[2] = p1[0]; a[3] = p1[1];
  };
  auto SPLITG = [&](f32x4 (&a)[4], float s0, float s1,
                    f16x8& h0, f16x8& l0, f16x8& h1, f16x8& l1) {
#pragma unroll
    for (int j = 0; j < 4; ++j) {
      float v; half_t x;
      v = a[0][j]*s0; x = (half_t)v; h0[j]   = x; l0[j]   = (half_t)(v - (float)x);
      v = a[1][j]*s0; x = (half_t)v; h0[j+4] = x; l0[j+4] = (half_t)(v - (float)x);
      v = a[2][j]*s1; x = (half_t)v; h1[j]   = x; l1[j]   = (half_t)(v - (float)x);
      v = a[3][j]*s1; x = (half_t)v; h1[j+4] = x; l1[j+4] = (half_t)(v - (float)x);
    }
  };

  f32x4 acc[2][8];
#pragma unroll
  for (int rg = 0; rg < 2; ++rg)
#pragma unroll
    for (int fn = 0; fn < 8; ++fn) acc[rg][fn] = f32x4{0.f, 0.f, 0.f, 0.f};

  LA(0, a0); LA(1, a1);

  for (int q = 0; q < 6; ++q) {                 // 6 phases x 4 chunks = chunks 0..23
    const float sq0 = gbuf[(size_t)(r0 + l15)*6 + q] * 16.f;
    const float sq1 = gbuf[(size_t)(r0 + 16 + l15)*6 + q] * 16.f;
    __syncthreads();
#pragma unroll
    for (int p = 0; p < 4; ++p) {
      const half_t* sp = Nf + ((size_t)(q*4 + p)*16 + fn0)*512;
#pragma unroll
      for (int i = 0; i < 2; ++i)
        gl16(sp + i*2048 + tid*8, (char*)Bs + p*8192 + i*4096 + wid*1024);
    }
    __syncthreads();
#pragma unroll
    for (int p = 0; p < 4; ++p) {
      const int t = q*4 + p;
      f16x8 h0, l0, h1, l1;
      if (p & 1) { SPLITG(a1, sq0, sq1, h0, l0, h1, l1); LA(t + 2, a1); }
      else       { SPLITG(a0, sq0, sq1, h0, l0, h1, l1); LA(t + 2, a0); }
#pragma unroll
      for (int fn = 0; fn < 8; ++fn) {
        f16x8 b = asH(Bs[(p*8 + fn)*64 + lane]);
        acc[0][fn] = MFMA16(h0, b, acc[0][fn], 0, 0, 0);
        acc[0][fn] = MFMA16(l0, b, acc[0][fn], 0, 0, 0);
        acc[1][fn] = MFMA16(h1, b, acc[1][fn], 0, 0, 0);
        acc[1][fn] = MFMA16(l1, b, acc[1][fn], 0, 0, 0);
      }
    }
  }

  // tail chunk 24: A = gate one-hot (cols 768..773 = cvec)
  __syncthreads();
  {
    const half_t* sT = Nf + ((size_t)24*16 + fn0)*512;
#pragma unroll
    for (int i = 0; i < 2; ++i)
      gl16(sT + i*2048 + tid*8, (char*)Bs + i*4096 + wid*1024);
  }
  __syncthreads();
  {
    f16x8 h0, h1;
#pragma unroll
    for (int j = 0; j < 8; ++j) {
      h0[j] = (l4 == 0 && j < 6) ? (half_t)(gbuf[(size_t)(r0 + l15)*6 + j]*16.f) : (half_t)0.f;
      h1[j] = (l4 == 0 && j < 6) ? (half_t)(gbuf[(size_t)(r0 + 16 + l15)*6 + j]*16.f) : (half_t)0.f;
    }
#pragma unroll
    for (int fn = 0; fn < 8; ++fn) {
      f16x8 b = asH(Bs[fn*64 + lane]);
      acc[0][fn] = MFMA16(h0, b, acc[0][fn], 0, 0, 0);
      acc[1][fn] = MFMA16(h1, b, acc[1][fn], 0, 0, 0);
    }
  }

  float bc[8];
#pragma unroll
  for (int fn = 0; fn < 8; ++fn) bc[fn] = bias[colOff + fn*16 + l15];
#pragma unroll
  for (int rg = 0; rg < 2; ++rg)
#pragma unroll
    for (int fn = 0; fn < 8; ++fn)
#pragma unroll
      for (int r = 0; r < 4; ++r) {
        float v = acc[rg][fn][r]*(1.f/65536.f) + bc[fn];
        v = fmaxf(v, 0.f) * 256.f;                    // pre-scale h1 for f16
        const int grow = r0 + rg*16 + l4*4 + r;
        h1h[(size_t)grow*256 + colOff + fn*16 + l15] = (half_t)v;
      }
}

// ================= f2: phase LDS B, f16 A, K=256 (2 phases), fused head =================
__global__ __launch_bounds__(256, 3)
void k_f2(const half_t* __restrict__ h1h, const half_t* __restrict__ WF,
          const float* __restrict__ bias, const float* __restrict__ Wout,
          float* __restrict__ part)
{
  __shared__ f32x4 Bs[2048];
  const int tid = threadIdx.x;
  const int row0 = blockIdx.x * 128;
  const int colOff = blockIdx.y * 128;
  const int fn0 = colOff >> 4;
  const int lane = tid & 63, wid = tid >> 6;
  const int l15 = lane & 15, l4 = lane >> 4;
  const int r0 = row0 + wid*32;

  const half_t* hr0 = h1h + (size_t)(r0 + l15)*256 + l4*8;
  const half_t* hr1 = h1h + (size_t)(r0 + 16 + l15)*256 + l4*8;

  f16x8 a0[2], a1[2];
  auto LA = [&](int t, f16x8 (&a)[2]) {
    const int tc = (t < 8) ? t : 7;
    a[0] = *reinterpret_cast<const f16x8*>(hr0 + tc*32);
    a[1] = *reinterpret_cast<const f16x8*>(hr1 + tc*32);
  };

  f32x4 acc[2][8];
#pragma unroll
  for (int rg = 0; rg < 2; ++rg)
#pragma unroll
    for (int fn = 0; fn < 8; ++fn) acc[rg][fn] = f32x4{0.f, 0.f, 0.f, 0.f};

  LA(0, a0); LA(1, a1);

  for (int q = 0; q < 2; ++q) {
    __syncthreads();
#pragma unroll
    for (int p = 0; p < 4; ++p) {
      const half_t* sp = WF + ((size_t)(q*4 + p)*16 + fn0)*512;
#pragma unroll
      for (int i = 0; i < 2; ++i)
        gl16(sp + i*2048 + tid*8, (char*)Bs + p*8192 + i*4096 + wid*1024);
    }
    __syncthreads();
#pragma unroll
    for (int p = 0; p < 4; ++p) {
      const int t = q*4 + p;
      f16x8 h0, h1;
      if (p & 1) { h0 = a1[0]; h1 = a1[1]; LA(t + 2, a1); }
      else       { h0 = a0[0]; h1 = a0[1]; LA(t + 2, a0); }
#pragma unroll
      for (int fn = 0; fn < 8; ++fn) {
        f16x8 b = asH(Bs[(p*8 + fn)*64 + lane]);
        acc[0][fn] = MFMA16(h0, b, acc[0][fn], 0, 0, 0);
        acc[1][fn] = MFMA16(h1, b, acc[1][fn], 0, 0, 0);
      }
    }
  }

  // epilogue: relu(h2), partial dot with Wout over this block's 128 cols
  float bc[8], w0[8], w1[8];
#pragma unroll
  for (int fn = 0; fn < 8; ++fn) {
    const int c = colOff + fn*16 + l15;
    bc[fn] = bias[c]; w0[fn] = Wout[c]; w1[fn] = Wout[256 + c];
  }
#pragma unroll
  for (int rg = 0; rg < 2; ++rg)
#pragma unroll
    for (int r = 0; r < 4; ++r) {
      float s0 = 0.f, s1 = 0.f;
#pragma unroll
      for (int fn = 0; fn < 8; ++fn) {
        float hv = fmaxf(acc[rg][fn][r]*(1.f/65536.f) + bc[fn], 0.f);
        s0 = fmaf(hv, w0[fn], s0);
        s1 = fmaf(hv, w1[fn], s1);
      }
#pragma unroll
      for (int m = 1; m <= 8; m <<= 1) { s0 += __shfl_xor(s0, m); s1 += __shfl_xor(s1, m); }
      if (l15 == rg*4 + r) {
        const int grow = r0 + rg*16 + l4*4 + r;
        float* pp = part + ((size_t)blockIdx.y*PB + grow)*2;
        pp[0] = s0; pp[1] = s1;
      }
    }
}

__global__ void k_comb(const float* __restrict__ part, const float* __restrict__ bout,
                       float* __restrict__ out)
{
  const int id = blockIdx.x*256 + threadIdx.x;
  const int j = id & 1;
  float s = bout[j];
#pragma unroll
  for (int s2 = 0; s2 < 2; ++s2) s += part[(size_t)s2*PB*2 + id];
  out[id] = s;
}

} // namespace

extern "C" void kernel_launch(void* const* d_in, const int* in_sizes, int n_in,
                              void* d_out, int out_size, void* d_ws, size_t ws_size,
                              hipStream_t stream)
{
  const float* xt   = (const float*)d_in[0];
  const float* xv   = (const float*)d_in[1];
  const float* xa   = (const float*)d_in[2];
  const float* Wt   = (const float*)d_in[3];
  const float* bt   = (const float*)d_in[4];
  const float* lnwt = (const float*)d_in[5];
  const float* lnbt = (const float*)d_in[6];
  const float* Wv   = (const float*)d_in[7];
  const float* bv   = (const float*)d_in[8];
  const float* lnwv = (const float*)d_in[9];
  const float* lnbv = (const float*)d_in[10];
  const float* Wa   = (const float*)d_in[11];
  const float* ba   = (const float*)d_in[12];
  const float* lnwa = (const float*)d_in[13];
  const float* lnba = (const float*)d_in[14];
  const float* Wqkv = (const float*)d_in[15];
  const float* bqkv = (const float*)d_in[16];
  const float* Wo   = (const float*)d_in[17];
  const float* bo   = (const float*)d_in[18];
  const float* Wg   = (const float*)d_in[19];
  const float* bg   = (const float*)d_in[20];
  const float* Wf1  = (const float*)d_in[21];
  const float* bf1  = (const float*)d_in[22];
  const float* Wf2  = (const float*)d_in[23];
  const float* bf2  = (const float*)d_in[24];
  const float* Woutp= (const float*)d_in[25];
  const float* boutp= (const float*)d_in[26];
  float* out = (float*)d_out;

  float* ws   = (float*)d_ws;
  float* tva  = ws;                              // PB*384 f32
  float* g    = tva  + (size_t)PB*384;           // PB*6
  float* h1pf = g    + (size_t)PB*6;             // PB*128 f32 (h1 halfs PB*256)
  float* M    = h1pf + (size_t)PB*128;           // 98304
  float* beff = M    + 98304;                    // 768
  half_t* Wft = (half_t*)(beff + 768);           // 98304 h (12 phases x 8192)
  half_t* Wfv = Wft + 98304;                     // 65536 h
  half_t* Wfa = Wfv + 65536;                     // 49152 h
  half_t* Nf  = Wfa + 49152;                     // 204800 h (25 chunks x 16 x 512)
  half_t* WF2 = Nf + 204800;                     // 65536 h
  float* Ghat = (float*)(WF2 + 65536);           // 2304
  float* svec = Ghat + 2304;                     // 8
  half_t* h1h = (half_t*)h1pf;
  float* zpart = h1pf;                           // 3*PB*6, dead before f1 writes h1h
  float* part  = tva;                            // 2*PB*2, tva dead before f2

  // weight composition + fragment-major single-plane splits (merged launches)
  k_weff<<<768, 128, 0, stream>>>(Wqkv, bqkv, Wo, bo, M, beff);
  k_nbig2<<<1536, 128, 0, stream>>>(Wf1, M, beff, Nf);
  k_gsv<<<24, 128, 0, stream>>>(M, Wg, beff, bg, Ghat, svec);
  k_splitall<<<1088, 256, 0, stream>>>(Wt, Wv, Wa, Wf2, Wft, Wfv, Wfa, WF2);

  // merged projections (fused LN+ReLU+gate-partials)
  k_proj<<<dim3(256, 3), 256, 0, stream>>>(xt, xv, xa, Wft, Wfv, Wfa,
                                           bt, lnwt, lnbt, bv, lnwv, lnbv, ba, lnwa, lnba,
                                           Ghat, tva, zpart);

  // gate
  k_gate2<<<PB/256, 256, 0, stream>>>(zpart, svec, g);

  // f1 (gated fused branch+f1, cvec folded), f2 (fused head partials), combine
  k_f1<<<dim3(256, 2), 256, 0, stream>>>(tva, Nf, g, bf1, h1h);
  k_f2<<<dim3(256, 2), 256, 0, stream>>>(h1h, WF2, bf2, Woutp, part);
  k_comb<<<256, 256, 0, stream>>>(part, boutp, out);
}